// Round 1
// baseline (1033.557 us; speedup 1.0000x reference)
//
#include <hip/hip_runtime.h>
#include <hip/hip_bf16.h>
#include <math.h>

#define NN 100000
#define EE 1600000
#define DD 256
#define DEE 8
#define HF 128           // H*F
#define NEG_SLOPE 0.2f

// ---------------------------------------------------------------------------
// GEMM: out[m][n] = sum_k A[m][k] * W[n][k]   (W row-major [128][K])
// MODE 0: plain store        (h_src)
// MODE 1: + bias             (h_dst)
// MODE 2: relu(acc+bias) + out[m][n] in-place (ngnn + residual)
// Block: 256 thr (16x16), thread tile 8x8, block tile 128x128, K-chunk 32.
// ---------------------------------------------------------------------------
template<int K, int MODE>
__global__ __launch_bounds__(256) void gemm_kernel(
    const float* __restrict__ A,
    const float* __restrict__ W,
    const float* __restrict__ bias,
    float* __restrict__ out)
{
    __shared__ float As[128 * 36];   // [m][k], pad to 36 for bank spread + f4 align
    __shared__ float Bs[32 * 132];   // [k][n], pad to 132

    const int tid = threadIdx.x;
    const int tx = tid & 15, ty = tid >> 4;
    const int m0 = blockIdx.x * 128;

    float acc[8][8];
#pragma unroll
    for (int i = 0; i < 8; ++i)
#pragma unroll
        for (int j = 0; j < 8; ++j) acc[i][j] = 0.f;

    for (int k0 = 0; k0 < K; k0 += 32) {
#pragma unroll
        for (int l = 0; l < 4; ++l) {
            int idx = l * 256 + tid;
            int ml = idx >> 3, kq = idx & 7;
            int m = m0 + ml;
            float4 v = make_float4(0.f, 0.f, 0.f, 0.f);
            if (m < NN) v = *(const float4*)(A + (size_t)m * K + k0 + kq * 4);
            *(float4*)&As[ml * 36 + kq * 4] = v;
        }
#pragma unroll
        for (int l = 0; l < 4; ++l) {
            int idx = l * 256 + tid;
            int nl = idx >> 3, kq = idx & 7;
            float4 v = *(const float4*)(W + (size_t)nl * K + k0 + kq * 4);
            Bs[(kq * 4 + 0) * 132 + nl] = v.x;
            Bs[(kq * 4 + 1) * 132 + nl] = v.y;
            Bs[(kq * 4 + 2) * 132 + nl] = v.z;
            Bs[(kq * 4 + 3) * 132 + nl] = v.w;
        }
        __syncthreads();
#pragma unroll
        for (int kk = 0; kk < 32; ++kk) {
            float a[8], b[8];
#pragma unroll
            for (int i = 0; i < 4; ++i) {
                a[i]     = As[(ty * 4 + i) * 36 + kk];
                a[i + 4] = As[(64 + ty * 4 + i) * 36 + kk];
            }
            float4 b0 = *(float4*)&Bs[kk * 132 + tx * 4];
            float4 b1 = *(float4*)&Bs[kk * 132 + 64 + tx * 4];
            b[0] = b0.x; b[1] = b0.y; b[2] = b0.z; b[3] = b0.w;
            b[4] = b1.x; b[5] = b1.y; b[6] = b1.z; b[7] = b1.w;
#pragma unroll
            for (int i = 0; i < 8; ++i)
#pragma unroll
                for (int j = 0; j < 8; ++j)
                    acc[i][j] = fmaf(a[i], b[j], acc[i][j]);
        }
        __syncthreads();
    }

    float4 bv0 = make_float4(0.f, 0.f, 0.f, 0.f), bv1 = bv0;
    if (MODE >= 1) {
        bv0 = *(const float4*)(bias + tx * 4);
        bv1 = *(const float4*)(bias + 64 + tx * 4);
    }
#pragma unroll
    for (int i = 0; i < 8; ++i) {
        int mrow = (i < 4) ? (ty * 4 + i) : (64 + ty * 4 + (i - 4));
        int m = m0 + mrow;
        if (m >= NN) continue;
        float4 v0 = make_float4(acc[i][0], acc[i][1], acc[i][2], acc[i][3]);
        float4 v1 = make_float4(acc[i][4], acc[i][5], acc[i][6], acc[i][7]);
        if (MODE >= 1) {
            v0.x += bv0.x; v0.y += bv0.y; v0.z += bv0.z; v0.w += bv0.w;
            v1.x += bv1.x; v1.y += bv1.y; v1.z += bv1.z; v1.w += bv1.w;
        }
        float* p0 = out + (size_t)m * HF + tx * 4;
        float* p1 = out + (size_t)m * HF + 64 + tx * 4;
        if (MODE == 2) {
            v0.x = fmaxf(v0.x, 0.f); v0.y = fmaxf(v0.y, 0.f);
            v0.z = fmaxf(v0.z, 0.f); v0.w = fmaxf(v0.w, 0.f);
            v1.x = fmaxf(v1.x, 0.f); v1.y = fmaxf(v1.y, 0.f);
            v1.z = fmaxf(v1.z, 0.f); v1.w = fmaxf(v1.w, 0.f);
            float4 r0 = *(float4*)p0;
            float4 r1 = *(float4*)p1;
            v0.x += r0.x; v0.y += r0.y; v0.z += r0.z; v0.w += r0.w;
            v1.x += r1.x; v1.y += r1.y; v1.z += r1.z; v1.w += r1.w;
        }
        *(float4*)p0 = v0;
        *(float4*)p1 = v1;
    }
}

// ---------------------------------------------------------------------------
// a_src[n][h] = feat[n] . W_attn_src[h] ; a_dst likewise. One wave per node.
// ---------------------------------------------------------------------------
__global__ __launch_bounds__(256) void attn_logits_kernel(
    const float* __restrict__ feat,
    const float* __restrict__ Was, const float* __restrict__ Wad,
    float* __restrict__ a_src, float* __restrict__ a_dst)
{
    int wave = threadIdx.x >> 6, lane = threadIdx.x & 63;
    int node = blockIdx.x * 4 + wave;
    if (node >= NN) return;
    float4 f = *(const float4*)(feat + (size_t)node * DD + lane * 4);
    float4 w0 = *(const float4*)(Was + 0 * DD + lane * 4);
    float4 w1 = *(const float4*)(Was + 1 * DD + lane * 4);
    float4 w2 = *(const float4*)(Wad + 0 * DD + lane * 4);
    float4 w3 = *(const float4*)(Wad + 1 * DD + lane * 4);
    float p0 = f.x * w0.x + f.y * w0.y + f.z * w0.z + f.w * w0.w;
    float p1 = f.x * w1.x + f.y * w1.y + f.z * w1.z + f.w * w1.w;
    float p2 = f.x * w2.x + f.y * w2.y + f.z * w2.z + f.w * w2.w;
    float p3 = f.x * w3.x + f.y * w3.y + f.z * w3.z + f.w * w3.w;
#pragma unroll
    for (int o = 32; o > 0; o >>= 1) {
        p0 += __shfl_xor(p0, o);
        p1 += __shfl_xor(p1, o);
        p2 += __shfl_xor(p2, o);
        p3 += __shfl_xor(p3, o);
    }
    if (lane == 0) {
        a_src[node * 2 + 0] = p0; a_src[node * 2 + 1] = p1;
        a_dst[node * 2 + 0] = p2; a_dst[node * 2 + 1] = p3;
    }
}

// ---------------------------------------------------------------------------
// CSR build
// ---------------------------------------------------------------------------
__global__ __launch_bounds__(256) void hist_kernel(
    const int* __restrict__ edge_dst, int* __restrict__ deg)
{
    int i = blockIdx.x * 256 + threadIdx.x;
    if (i < EE) atomicAdd(&deg[edge_dst[i]], 1);
}

#define SCAN_ELEMS 1024
__global__ __launch_bounds__(256) void scan1_kernel(
    const int* __restrict__ deg, int* __restrict__ offsets, int* __restrict__ blockSums)
{
    __shared__ int sd[256];
    int tid = threadIdx.x;
    int base = blockIdx.x * SCAN_ELEMS + tid * 4;
    int v[4];
#pragma unroll
    for (int c = 0; c < 4; ++c) v[c] = (base + c < NN) ? deg[base + c] : 0;
    int tsum = v[0] + v[1] + v[2] + v[3];
    sd[tid] = tsum;
    __syncthreads();
    for (int o = 1; o < 256; o <<= 1) {
        int x = (tid >= o) ? sd[tid - o] : 0;
        __syncthreads();
        sd[tid] += x;
        __syncthreads();
    }
    int excl = sd[tid] - tsum;
    int run = excl;
#pragma unroll
    for (int c = 0; c < 4; ++c) {
        if (base + c < NN) offsets[base + c] = run;
        run += v[c];
    }
    if (tid == 255) blockSums[blockIdx.x] = sd[255];
}

__global__ __launch_bounds__(128) void scan2_kernel(int* __restrict__ blockSums, int nb)
{
    __shared__ int sd[128];
    int tid = threadIdx.x;
    int tv = (tid < nb) ? blockSums[tid] : 0;
    sd[tid] = tv;
    __syncthreads();
    for (int o = 1; o < 128; o <<= 1) {
        int x = (tid >= o) ? sd[tid - o] : 0;
        __syncthreads();
        sd[tid] += x;
        __syncthreads();
    }
    if (tid < nb) blockSums[tid] = sd[tid] - tv;   // exclusive
}

__global__ __launch_bounds__(256) void scan3_kernel(
    int* __restrict__ offsets, int* __restrict__ cursor, const int* __restrict__ blockSums)
{
    int tid = threadIdx.x;
    int base = blockIdx.x * SCAN_ELEMS + tid * 4;
    int add = blockSums[blockIdx.x];
#pragma unroll
    for (int c = 0; c < 4; ++c) {
        if (base + c < NN) {
            int v = offsets[base + c] + add;
            offsets[base + c] = v;
            cursor[base + c] = v;
        }
    }
    if (blockIdx.x == 0 && tid == 0) offsets[NN] = EE;
}

__global__ __launch_bounds__(256) void scatter_kernel(
    const int* __restrict__ edge_dst, int* __restrict__ cursor, int* __restrict__ edge_ids)
{
    int i = blockIdx.x * 256 + threadIdx.x;
    if (i < EE) {
        int d = edge_dst[i];
        int pos = atomicAdd(&cursor[d], 1);
        edge_ids[pos] = i;
    }
}

// ---------------------------------------------------------------------------
// e[i][h] = leakyrelu(a_src[src] + a_dst[dst] + feat_edge[i].W_attn_edge[h])
// ---------------------------------------------------------------------------
__global__ __launch_bounds__(256) void edge_score_kernel(
    const float* __restrict__ feat_edge,
    const int* __restrict__ edge_src, const int* __restrict__ edge_dst,
    const float* __restrict__ a_src, const float* __restrict__ a_dst,
    const float* __restrict__ Wae, float* __restrict__ eb)
{
    int i = blockIdx.x * 256 + threadIdx.x;
    if (i >= EE) return;
    int s = edge_src[i], d = edge_dst[i];
    float4 e0 = ((const float4*)feat_edge)[i * 2 + 0];
    float4 e1 = ((const float4*)feat_edge)[i * 2 + 1];
    float4 w00 = ((const float4*)Wae)[0], w01 = ((const float4*)Wae)[1];
    float4 w10 = ((const float4*)Wae)[2], w11 = ((const float4*)Wae)[3];
    float ae0 = e0.x*w00.x + e0.y*w00.y + e0.z*w00.z + e0.w*w00.w
              + e1.x*w01.x + e1.y*w01.y + e1.z*w01.z + e1.w*w01.w;
    float ae1 = e0.x*w10.x + e0.y*w10.y + e0.z*w10.z + e0.w*w10.w
              + e1.x*w11.x + e1.y*w11.y + e1.z*w11.z + e1.w*w11.w;
    float v0 = a_src[s * 2 + 0] + a_dst[d * 2 + 0] + ae0;
    float v1 = a_src[s * 2 + 1] + a_dst[d * 2 + 1] + ae1;
    v0 = (v0 >= 0.f) ? v0 : NEG_SLOPE * v0;
    v1 = (v1 >= 0.f) ? v1 : NEG_SLOPE * v1;
    ((float2*)eb)[i] = make_float2(v0, v1);
}

// ---------------------------------------------------------------------------
// Edge softmax per dst node (one wave per node, CSR). e updated in place.
// ---------------------------------------------------------------------------
__global__ __launch_bounds__(256) void softmax_kernel(
    const int* __restrict__ offsets, const int* __restrict__ edge_ids,
    float* __restrict__ eb)
{
    int wave = threadIdx.x >> 6, lane = threadIdx.x & 63;
    int node = blockIdx.x * 4 + wave;
    if (node >= NN) return;
    int off = offsets[node], end = offsets[node + 1];
    float2* e2 = (float2*)eb;

    float m0 = -INFINITY, m1 = -INFINITY;
    for (int j = off + lane; j < end; j += 64) {
        float2 v = e2[edge_ids[j]];
        m0 = fmaxf(m0, v.x); m1 = fmaxf(m1, v.y);
    }
#pragma unroll
    for (int o = 32; o > 0; o >>= 1) {
        m0 = fmaxf(m0, __shfl_xor(m0, o));
        m1 = fmaxf(m1, __shfl_xor(m1, o));
    }
    float z0 = 0.f, z1 = 0.f;
    for (int j = off + lane; j < end; j += 64) {
        int eid = edge_ids[j];
        float2 v = e2[eid];
        v.x = __expf(v.x - m0); v.y = __expf(v.y - m1);
        z0 += v.x; z1 += v.y;
        e2[eid] = v;
    }
#pragma unroll
    for (int o = 32; o > 0; o >>= 1) {
        z0 += __shfl_xor(z0, o);
        z1 += __shfl_xor(z1, o);
    }
    float i0 = (z0 > 0.f) ? 1.f / z0 : 0.f;
    float i1 = (z1 > 0.f) ? 1.f / z1 : 0.f;
    for (int j = off + lane; j < end; j += 64) {
        int eid = edge_ids[j];
        float2 v = e2[eid];
        v.x *= i0; v.y *= i1;
        e2[eid] = v;
    }
}

// ---------------------------------------------------------------------------
// agg[n][t] = sum_{edges into n} a[eid][t>>6] * h_src[src][t]  (block/node)
// ---------------------------------------------------------------------------
__global__ __launch_bounds__(128) void aggregate_kernel(
    const int* __restrict__ offsets, const int* __restrict__ edge_ids,
    const int* __restrict__ edge_src,
    const float* __restrict__ eb, const float* __restrict__ h_src,
    float* __restrict__ agg)
{
    int node = blockIdx.x;
    int t = threadIdx.x;
    int h = t >> 6;
    int off = offsets[node], end = offsets[node + 1];
    float acc0 = 0.f, acc1 = 0.f;
    int j = off;
    for (; j + 1 < end; j += 2) {
        int e0 = edge_ids[j], e1 = edge_ids[j + 1];
        int s0 = edge_src[e0], s1 = edge_src[e1];
        float a0 = eb[e0 * 2 + h], a1 = eb[e1 * 2 + h];
        acc0 = fmaf(a0, h_src[(size_t)s0 * HF + t], acc0);
        acc1 = fmaf(a1, h_src[(size_t)s1 * HF + t], acc1);
    }
    if (j < end) {
        int e0 = edge_ids[j];
        int s0 = edge_src[e0];
        acc0 = fmaf(eb[e0 * 2 + h], h_src[(size_t)s0 * HF + t], acc0);
    }
    agg[(size_t)node * HF + t] = acc0 + acc1;
}

// ---------------------------------------------------------------------------
extern "C" void kernel_launch(void* const* d_in, const int* in_sizes, int n_in,
                              void* d_out, int out_size, void* d_ws, size_t ws_size,
                              hipStream_t stream) {
    (void)in_sizes; (void)n_in; (void)out_size; (void)ws_size;
    const float* feat_src  = (const float*)d_in[0];
    const float* feat_edge = (const float*)d_in[1];
    const int*   edge_src  = (const int*)d_in[2];
    const int*   edge_dst  = (const int*)d_in[3];
    const float* W_src     = (const float*)d_in[4];
    const float* W_dst     = (const float*)d_in[5];
    const float* b_dst     = (const float*)d_in[6];
    const float* W_attn_src  = (const float*)d_in[7];
    const float* W_attn_dst  = (const float*)d_in[8];
    const float* W_attn_edge = (const float*)d_in[9];
    const float* W_ngnn    = (const float*)d_in[10];
    const float* b_ngnn    = (const float*)d_in[11];
    float* out = (float*)d_out;

    // workspace carve-up
    char* base = (char*)d_ws;
    size_t off = 0;
    auto take = [&](size_t bytes) -> void* {
        void* p = base + off;
        off = (off + bytes + 511) & ~(size_t)511;
        return p;
    };
    float* h_src_b  = (float*)take((size_t)NN * HF * 4);   // 51.2 MB
    float* agg_b    = (float*)take((size_t)NN * HF * 4);   // 51.2 MB
    float* eb       = (float*)take((size_t)EE * 2 * 4);    // 12.8 MB
    float* a_src_b  = (float*)take((size_t)NN * 2 * 4);
    float* a_dst_b  = (float*)take((size_t)NN * 2 * 4);
    int*   deg      = (int*)take((size_t)NN * 4);
    int*   offsets  = (int*)take((size_t)(NN + 1) * 4);
    int*   cursor   = (int*)take((size_t)NN * 4);
    int*   edge_ids = (int*)take((size_t)EE * 4);
    int*   blockSums= (int*)take(512);

    const int NB_SCAN = (NN + SCAN_ELEMS - 1) / SCAN_ELEMS;   // 98
    const int GB_E = (EE + 255) / 256;                        // 6250
    const int GB_M = (NN + 127) / 128;                        // 782
    const int GB_N4 = (NN + 3) / 4;                           // 25000

    // CSR build
    hipMemsetAsync(deg, 0, (size_t)NN * 4, stream);
    hipLaunchKernelGGL(hist_kernel, dim3(GB_E), dim3(256), 0, stream, edge_dst, deg);
    hipLaunchKernelGGL(scan1_kernel, dim3(NB_SCAN), dim3(256), 0, stream, deg, offsets, blockSums);
    hipLaunchKernelGGL(scan2_kernel, dim3(1), dim3(128), 0, stream, blockSums, NB_SCAN);
    hipLaunchKernelGGL(scan3_kernel, dim3(NB_SCAN), dim3(256), 0, stream, offsets, cursor, blockSums);
    hipLaunchKernelGGL(scatter_kernel, dim3(GB_E), dim3(256), 0, stream, edge_dst, cursor, edge_ids);

    // projections
    hipLaunchKernelGGL((gemm_kernel<DD, 0>), dim3(GB_M), dim3(256), 0, stream,
                       feat_src, W_src, (const float*)nullptr, h_src_b);
    hipLaunchKernelGGL((gemm_kernel<DD, 1>), dim3(GB_M), dim3(256), 0, stream,
                       feat_src, W_dst, b_dst, out);          // h_dst staged in d_out
    hipLaunchKernelGGL(attn_logits_kernel, dim3(GB_N4), dim3(256), 0, stream,
                       feat_src, W_attn_src, W_attn_dst, a_src_b, a_dst_b);

    // edge scores + softmax
    hipLaunchKernelGGL(edge_score_kernel, dim3(GB_E), dim3(256), 0, stream,
                       feat_edge, edge_src, edge_dst, a_src_b, a_dst_b, W_attn_edge, eb);
    hipLaunchKernelGGL(softmax_kernel, dim3(GB_N4), dim3(256), 0, stream,
                       offsets, edge_ids, eb);

    // aggregation
    hipLaunchKernelGGL(aggregate_kernel, dim3(NN), dim3(128), 0, stream,
                       offsets, edge_ids, edge_src, eb, h_src_b, agg_b);

    // ngnn + relu + residual (in-place on d_out which holds h_dst)
    hipLaunchKernelGGL((gemm_kernel<HF, 2>), dim3(GB_M), dim3(256), 0, stream,
                       agg_b, W_ngnn, b_ngnn, out);
}

// Round 2
// 779.051 us; speedup vs baseline: 1.3267x; 1.3267x over previous
//
#include <hip/hip_runtime.h>
#include <hip/hip_bf16.h>
#include <math.h>

#define NN 100000
#define EE 1600000
#define DD 256
#define DEE 8
#define HF 128           // H*F
#define NEG_SLOPE 0.2f

typedef __bf16 bf16x8 __attribute__((ext_vector_type(8)));
typedef float  f32x4  __attribute__((ext_vector_type(4)));

__device__ inline ushort f2bf(float f) {          // round-to-nearest-even
    uint32_t x = __builtin_bit_cast(uint32_t, f);
    x += 0x7fffu + ((x >> 16) & 1u);
    return (ushort)(x >> 16);
}
__device__ inline float bf2f(ushort u) {
    uint32_t x = ((uint32_t)u) << 16;
    return __builtin_bit_cast(float, x);
}

__device__ inline void load_lds16(const void* g, void* l) {
    __builtin_amdgcn_global_load_lds(
        (const __attribute__((address_space(1))) void*)g,
        (__attribute__((address_space(3))) void*)l, 16, 0, 0);
}

// ---------------------------------------------------------------------------
// fp32 -> bf16 cast, 4 elems/thread
// ---------------------------------------------------------------------------
__global__ __launch_bounds__(256) void f2bf_kernel(
    const float* __restrict__ in, ushort* __restrict__ out, int n)
{
    int i = (blockIdx.x * 256 + threadIdx.x) * 4;
    if (i + 3 < n) {
        float4 v = *(const float4*)(in + i);
        ushort4 o;
        o.x = f2bf(v.x); o.y = f2bf(v.y); o.z = f2bf(v.z); o.w = f2bf(v.w);
        *(ushort4*)(out + i) = o;
    } else {
        for (int c = 0; c < 4 && i + c < n; ++c) out[i + c] = f2bf(in[i + c]);
    }
}

// ---------------------------------------------------------------------------
// MFMA GEMM: D[f][node] = sum_k Wb[f][k] * Xb[node][k]   (both bf16 [rows][K])
// Block = 256 thr (4 waves, 2x2), tile = 128 feats x 128 nodes, BK=32.
// MODE 0: store bf16 out[node][f]
// MODE 1: store bf16 out[node][f] = acc + bias[f]
// MODE 2: store fp32 out[node][f] = relu(acc + bias[f]) + bf2f(resid[node][f])
// ---------------------------------------------------------------------------
template<int K, int MODE>
__global__ __launch_bounds__(256) void mfma_gemm(
    const ushort* __restrict__ Wb,     // [128][K]
    const ushort* __restrict__ Xb,     // [NN][K]
    const float*  __restrict__ bias,   // [128] or null
    const ushort* __restrict__ resid,  // [NN][128] bf16 (MODE 2) or null
    void* __restrict__ outp)
{
    __shared__ ushort As[128 * 32];    // W slab   [f][k]
    __shared__ ushort Bs[128 * 32];    // node slab[n][k]

    const int tid  = threadIdx.x;
    const int lane = tid & 63, wv = tid >> 6;
    const int wm = wv >> 1, wn = wv & 1;       // wm: feat half, wn: node half
    const int r = lane & 15, quad = lane >> 4;
    const int m0 = blockIdx.x * 128;           // node base

    f32x4 acc[4][4] = {};

    for (int k0 = 0; k0 < K; k0 += 32) {
#pragma unroll
        for (int t = 0; t < 2; ++t) {
            int is  = wv + t * 4;                      // staging issue 0..7
            int row = is * 16 + (lane >> 2);
            int ko  = k0 + (lane & 3) * 8;             // 8 ushorts = 16 B
            load_lds16(Wb + (size_t)row * K + ko, &As[is * 512]);
            int gm = m0 + row; gm = gm < NN ? gm : NN - 1;
            load_lds16(Xb + (size_t)gm * K + ko, &Bs[is * 512]);
        }
        __syncthreads();
        bf16x8 a[4], b[4];
#pragma unroll
        for (int i = 0; i < 4; ++i) {
            a[i] = __builtin_bit_cast(bf16x8,
                   *(const f32x4*)&As[(wm * 64 + i * 16 + r) * 32 + quad * 8]);
            b[i] = __builtin_bit_cast(bf16x8,
                   *(const f32x4*)&Bs[(wn * 64 + i * 16 + r) * 32 + quad * 8]);
        }
#pragma unroll
        for (int i = 0; i < 4; ++i)
#pragma unroll
            for (int j = 0; j < 4; ++j)
                acc[i][j] = __builtin_amdgcn_mfma_f32_16x16x32_bf16(
                    a[i], b[j], acc[i][j], 0, 0, 0);
        __syncthreads();
    }

    // D layout: col(node offset)=lane&15, row(feat)=quad*4+reg
#pragma unroll
    for (int i = 0; i < 4; ++i) {
        int fbase = wm * 64 + i * 16 + quad * 4;     // 4 consecutive out-features
        float4 bv = make_float4(0.f, 0.f, 0.f, 0.f);
        if (MODE >= 1) bv = *(const float4*)(bias + fbase);
#pragma unroll
        for (int j = 0; j < 4; ++j) {
            int node = m0 + wn * 64 + j * 16 + r;
            if (node >= NN) continue;
            f32x4 v = acc[i][j];
            if (MODE >= 1) { v[0] += bv.x; v[1] += bv.y; v[2] += bv.z; v[3] += bv.w; }
            if (MODE == 2) {
                ushort4 rs = *(const ushort4*)(resid + (size_t)node * HF + fbase);
                float4 o;
                o.x = fmaxf(v[0], 0.f) + bf2f(rs.x);
                o.y = fmaxf(v[1], 0.f) + bf2f(rs.y);
                o.z = fmaxf(v[2], 0.f) + bf2f(rs.z);
                o.w = fmaxf(v[3], 0.f) + bf2f(rs.w);
                *(float4*)((float*)outp + (size_t)node * HF + fbase) = o;
            } else {
                ushort4 o;
                o.x = f2bf(v[0]); o.y = f2bf(v[1]); o.z = f2bf(v[2]); o.w = f2bf(v[3]);
                *(ushort4*)((ushort*)outp + (size_t)node * HF + fbase) = o;
            }
        }
    }
}

// ---------------------------------------------------------------------------
// a_src[n][h] = feat[n] . W_attn_src[h] ; a_dst likewise. One wave per node.
// ---------------------------------------------------------------------------
__global__ __launch_bounds__(256) void attn_logits_kernel(
    const float* __restrict__ feat,
    const float* __restrict__ Was, const float* __restrict__ Wad,
    float* __restrict__ a_src, float* __restrict__ a_dst)
{
    int wave = threadIdx.x >> 6, lane = threadIdx.x & 63;
    int node = blockIdx.x * 4 + wave;
    if (node >= NN) return;
    float4 f = *(const float4*)(feat + (size_t)node * DD + lane * 4);
    float4 w0 = *(const float4*)(Was + 0 * DD + lane * 4);
    float4 w1 = *(const float4*)(Was + 1 * DD + lane * 4);
    float4 w2 = *(const float4*)(Wad + 0 * DD + lane * 4);
    float4 w3 = *(const float4*)(Wad + 1 * DD + lane * 4);
    float p0 = f.x * w0.x + f.y * w0.y + f.z * w0.z + f.w * w0.w;
    float p1 = f.x * w1.x + f.y * w1.y + f.z * w1.z + f.w * w1.w;
    float p2 = f.x * w2.x + f.y * w2.y + f.z * w2.z + f.w * w2.w;
    float p3 = f.x * w3.x + f.y * w3.y + f.z * w3.z + f.w * w3.w;
#pragma unroll
    for (int o = 32; o > 0; o >>= 1) {
        p0 += __shfl_xor(p0, o);
        p1 += __shfl_xor(p1, o);
        p2 += __shfl_xor(p2, o);
        p3 += __shfl_xor(p3, o);
    }
    if (lane == 0) {
        a_src[node * 2 + 0] = p0; a_src[node * 2 + 1] = p1;
        a_dst[node * 2 + 0] = p2; a_dst[node * 2 + 1] = p3;
    }
}

// ---------------------------------------------------------------------------
// CSR build
// ---------------------------------------------------------------------------
__global__ __launch_bounds__(256) void hist_kernel(
    const int* __restrict__ edge_dst, int* __restrict__ deg)
{
    int i = blockIdx.x * 256 + threadIdx.x;
    if (i < EE) atomicAdd(&deg[edge_dst[i]], 1);
}

#define SCAN_ELEMS 1024
__global__ __launch_bounds__(256) void scan1_kernel(
    const int* __restrict__ deg, int* __restrict__ offsets, int* __restrict__ blockSums)
{
    __shared__ int sd[256];
    int tid = threadIdx.x;
    int base = blockIdx.x * SCAN_ELEMS + tid * 4;
    int v[4];
#pragma unroll
    for (int c = 0; c < 4; ++c) v[c] = (base + c < NN) ? deg[base + c] : 0;
    int tsum = v[0] + v[1] + v[2] + v[3];
    sd[tid] = tsum;
    __syncthreads();
    for (int o = 1; o < 256; o <<= 1) {
        int x = (tid >= o) ? sd[tid - o] : 0;
        __syncthreads();
        sd[tid] += x;
        __syncthreads();
    }
    int excl = sd[tid] - tsum;
    int run = excl;
#pragma unroll
    for (int c = 0; c < 4; ++c) {
        if (base + c < NN) offsets[base + c] = run;
        run += v[c];
    }
    if (tid == 255) blockSums[blockIdx.x] = sd[255];
}

__global__ __launch_bounds__(128) void scan2_kernel(int* __restrict__ blockSums, int nb)
{
    __shared__ int sd[128];
    int tid = threadIdx.x;
    int tv = (tid < nb) ? blockSums[tid] : 0;
    sd[tid] = tv;
    __syncthreads();
    for (int o = 1; o < 128; o <<= 1) {
        int x = (tid >= o) ? sd[tid - o] : 0;
        __syncthreads();
        sd[tid] += x;
        __syncthreads();
    }
    if (tid < nb) blockSums[tid] = sd[tid] - tv;   // exclusive
}

__global__ __launch_bounds__(256) void scan3_kernel(
    int* __restrict__ offsets, int* __restrict__ cursor, const int* __restrict__ blockSums)
{
    int tid = threadIdx.x;
    int base = blockIdx.x * SCAN_ELEMS + tid * 4;
    int add = blockSums[blockIdx.x];
#pragma unroll
    for (int c = 0; c < 4; ++c) {
        if (base + c < NN) {
            int v = offsets[base + c] + add;
            offsets[base + c] = v;
            cursor[base + c] = v;
        }
    }
    if (blockIdx.x == 0 && tid == 0) offsets[NN] = EE;
}

__global__ __launch_bounds__(256) void scatter_kernel(
    const int* __restrict__ edge_dst, int* __restrict__ cursor, int* __restrict__ edge_ids)
{
    int i = blockIdx.x * 256 + threadIdx.x;
    if (i < EE) {
        int d = edge_dst[i];
        int pos = atomicAdd(&cursor[d], 1);
        edge_ids[pos] = i;
    }
}

// ---------------------------------------------------------------------------
// e[i][h] = leakyrelu(a_src[src] + a_dst[dst] + feat_edge[i].W_attn_edge[h])
// ---------------------------------------------------------------------------
__global__ __launch_bounds__(256) void edge_score_kernel(
    const float* __restrict__ feat_edge,
    const int* __restrict__ edge_src, const int* __restrict__ edge_dst,
    const float* __restrict__ a_src, const float* __restrict__ a_dst,
    const float* __restrict__ Wae, float* __restrict__ eb)
{
    int i = blockIdx.x * 256 + threadIdx.x;
    if (i >= EE) return;
    int s = edge_src[i], d = edge_dst[i];
    float4 e0 = ((const float4*)feat_edge)[i * 2 + 0];
    float4 e1 = ((const float4*)feat_edge)[i * 2 + 1];
    float4 w00 = ((const float4*)Wae)[0], w01 = ((const float4*)Wae)[1];
    float4 w10 = ((const float4*)Wae)[2], w11 = ((const float4*)Wae)[3];
    float ae0 = e0.x*w00.x + e0.y*w00.y + e0.z*w00.z + e0.w*w00.w
              + e1.x*w01.x + e1.y*w01.y + e1.z*w01.z + e1.w*w01.w;
    float ae1 = e0.x*w10.x + e0.y*w10.y + e0.z*w10.z + e0.w*w10.w
              + e1.x*w11.x + e1.y*w11.y + e1.z*w11.z + e1.w*w11.w;
    float v0 = a_src[s * 2 + 0] + a_dst[d * 2 + 0] + ae0;
    float v1 = a_src[s * 2 + 1] + a_dst[d * 2 + 1] + ae1;
    v0 = (v0 >= 0.f) ? v0 : NEG_SLOPE * v0;
    v1 = (v1 >= 0.f) ? v1 : NEG_SLOPE * v1;
    ((float2*)eb)[i] = make_float2(v0, v1);
}

// ---------------------------------------------------------------------------
// Per-dst softmax, 2 passes: max, then exp+sum. eb <- exp(e-m); zinv <- 1/z.
// Normalization is folded into the aggregate kernel.
// ---------------------------------------------------------------------------
__global__ __launch_bounds__(256) void softmax_kernel(
    const int* __restrict__ offsets, const int* __restrict__ edge_ids,
    float* __restrict__ eb, float* __restrict__ zinv)
{
    int wave = threadIdx.x >> 6, lane = threadIdx.x & 63;
    int node = blockIdx.x * 4 + wave;
    if (node >= NN) return;
    int off = offsets[node], end = offsets[node + 1];
    float2* e2 = (float2*)eb;

    float m0 = -INFINITY, m1 = -INFINITY;
    for (int j = off + lane; j < end; j += 64) {
        float2 v = e2[edge_ids[j]];
        m0 = fmaxf(m0, v.x); m1 = fmaxf(m1, v.y);
    }
#pragma unroll
    for (int o = 32; o > 0; o >>= 1) {
        m0 = fmaxf(m0, __shfl_xor(m0, o));
        m1 = fmaxf(m1, __shfl_xor(m1, o));
    }
    float z0 = 0.f, z1 = 0.f;
    for (int j = off + lane; j < end; j += 64) {
        int eid = edge_ids[j];
        float2 v = e2[eid];
        v.x = __expf(v.x - m0); v.y = __expf(v.y - m1);
        z0 += v.x; z1 += v.y;
        e2[eid] = v;
    }
#pragma unroll
    for (int o = 32; o > 0; o >>= 1) {
        z0 += __shfl_xor(z0, o);
        z1 += __shfl_xor(z1, o);
    }
    if (lane == 0) {
        zinv[node * 2 + 0] = (z0 > 0.f) ? 1.f / z0 : 0.f;
        zinv[node * 2 + 1] = (z1 > 0.f) ? 1.f / z1 : 0.f;
    }
}

// ---------------------------------------------------------------------------
// agg[n][c] = zinv[n][c>>6] * sum_e ex[e][c>>6] * h_src[src_e][c]
// One wave per node; each lane owns cols {2*lane, 2*lane+1} (bf16x2 loads).
// ---------------------------------------------------------------------------
__global__ __launch_bounds__(256) void aggregate_kernel(
    const int* __restrict__ offsets, const int* __restrict__ edge_ids,
    const int* __restrict__ edge_src,
    const float* __restrict__ eb, const float* __restrict__ zinv,
    const ushort* __restrict__ hsrc, ushort* __restrict__ agg)
{
    int wave = threadIdx.x >> 6, lane = threadIdx.x & 63;
    int node = blockIdx.x * 4 + wave;
    if (node >= NN) return;
    int off = offsets[node], end = offsets[node + 1];
    int hh = lane >> 5;                       // cols 2*lane,2*lane+1 -> head
    const uint* h2 = (const uint*)hsrc;       // packed bf16x2
    float acc0 = 0.f, acc1 = 0.f;
    int j = off;
    for (; j + 1 < end; j += 2) {
        int e0 = edge_ids[j], e1 = edge_ids[j + 1];
        int s0 = edge_src[e0], s1 = edge_src[e1];
        float a0 = eb[e0 * 2 + hh], a1 = eb[e1 * 2 + hh];
        uint p0 = h2[(size_t)s0 * 64 + lane];
        uint p1 = h2[(size_t)s1 * 64 + lane];
        acc0 = fmaf(a0, bf2f((ushort)(p0 & 0xffff)), acc0);
        acc1 = fmaf(a0, bf2f((ushort)(p0 >> 16)),    acc1);
        acc0 = fmaf(a1, bf2f((ushort)(p1 & 0xffff)), acc0);
        acc1 = fmaf(a1, bf2f((ushort)(p1 >> 16)),    acc1);
    }
    if (j < end) {
        int e0 = edge_ids[j];
        int s0 = edge_src[e0];
        float a0 = eb[e0 * 2 + hh];
        uint p0 = h2[(size_t)s0 * 64 + lane];
        acc0 = fmaf(a0, bf2f((ushort)(p0 & 0xffff)), acc0);
        acc1 = fmaf(a0, bf2f((ushort)(p0 >> 16)),    acc1);
    }
    float zi = zinv[node * 2 + hh];
    uint outw = ((uint)f2bf(acc1 * zi) << 16) | (uint)f2bf(acc0 * zi);
    ((uint*)agg)[(size_t)node * 64 + lane] = outw;
}

// ---------------------------------------------------------------------------
extern "C" void kernel_launch(void* const* d_in, const int* in_sizes, int n_in,
                              void* d_out, int out_size, void* d_ws, size_t ws_size,
                              hipStream_t stream) {
    (void)in_sizes; (void)n_in; (void)out_size; (void)ws_size;
    const float* feat_src  = (const float*)d_in[0];
    const float* feat_edge = (const float*)d_in[1];
    const int*   edge_src  = (const int*)d_in[2];
    const int*   edge_dst  = (const int*)d_in[3];
    const float* W_src     = (const float*)d_in[4];
    const float* W_dst     = (const float*)d_in[5];
    const float* b_dst     = (const float*)d_in[6];
    const float* W_attn_src  = (const float*)d_in[7];
    const float* W_attn_dst  = (const float*)d_in[8];
    const float* W_attn_edge = (const float*)d_in[9];
    const float* W_ngnn    = (const float*)d_in[10];
    const float* b_ngnn    = (const float*)d_in[11];
    float* out = (float*)d_out;

    // workspace carve-up
    char* base = (char*)d_ws;
    size_t off = 0;
    auto take = [&](size_t bytes) -> void* {
        void* p = base + off;
        off = (off + bytes + 511) & ~(size_t)511;
        return p;
    };
    ushort* feat_bf  = (ushort*)take((size_t)NN * DD * 2);   // 51.2 MB (agg reuses)
    ushort* h_src_bf = (ushort*)take((size_t)NN * HF * 2);   // 25.6 MB
    ushort* h_dst_bf = (ushort*)take((size_t)NN * HF * 2);   // 25.6 MB
    float*  eb       = (float*)take((size_t)EE * 2 * 4);     // 12.8 MB
    float*  zinv     = (float*)take((size_t)NN * 2 * 4);
    float*  a_src_b  = (float*)take((size_t)NN * 2 * 4);
    float*  a_dst_b  = (float*)take((size_t)NN * 2 * 4);
    int*    deg      = (int*)take((size_t)NN * 4);
    int*    offsets  = (int*)take((size_t)(NN + 1) * 4);
    int*    cursor   = (int*)take((size_t)NN * 4);
    int*    edge_ids = (int*)take((size_t)EE * 4);
    int*    blockSums= (int*)take(512);
    ushort* Wsrc_bf  = (ushort*)take((size_t)HF * DD * 2);
    ushort* Wdst_bf  = (ushort*)take((size_t)HF * DD * 2);
    ushort* Wngnn_bf = (ushort*)take((size_t)HF * HF * 2);
    ushort* agg_bf   = feat_bf;   // reuse: feat_bf dead after proj GEMMs

    const int NB_SCAN = (NN + SCAN_ELEMS - 1) / SCAN_ELEMS;   // 98
    const int GB_E  = (EE + 255) / 256;                       // 6250
    const int GB_M  = (NN + 127) / 128;                       // 782
    const int GB_N4 = (NN + 3) / 4;                           // 25000

    // CSR build
    hipMemsetAsync(deg, 0, (size_t)NN * 4, stream);
    hipLaunchKernelGGL(hist_kernel, dim3(GB_E), dim3(256), 0, stream, edge_dst, deg);
    hipLaunchKernelGGL(scan1_kernel, dim3(NB_SCAN), dim3(256), 0, stream, deg, offsets, blockSums);
    hipLaunchKernelGGL(scan2_kernel, dim3(1), dim3(128), 0, stream, blockSums, NB_SCAN);
    hipLaunchKernelGGL(scan3_kernel, dim3(NB_SCAN), dim3(256), 0, stream, offsets, cursor, blockSums);
    hipLaunchKernelGGL(scatter_kernel, dim3(GB_E), dim3(256), 0, stream, edge_dst, cursor, edge_ids);

    // bf16 conversions
    hipLaunchKernelGGL(f2bf_kernel, dim3((NN * DD / 4 + 255) / 256), dim3(256), 0, stream,
                       feat_src, feat_bf, NN * DD);
    hipLaunchKernelGGL(f2bf_kernel, dim3((HF * DD / 4 + 255) / 256), dim3(256), 0, stream,
                       W_src, Wsrc_bf, HF * DD);
    hipLaunchKernelGGL(f2bf_kernel, dim3((HF * DD / 4 + 255) / 256), dim3(256), 0, stream,
                       W_dst, Wdst_bf, HF * DD);
    hipLaunchKernelGGL(f2bf_kernel, dim3((HF * HF / 4 + 255) / 256), dim3(256), 0, stream,
                       W_ngnn, Wngnn_bf, HF * HF);

    // projections (MFMA)
    hipLaunchKernelGGL((mfma_gemm<DD, 0>), dim3(GB_M), dim3(256), 0, stream,
                       Wsrc_bf, feat_bf, (const float*)nullptr, (const ushort*)nullptr, h_src_bf);
    hipLaunchKernelGGL((mfma_gemm<DD, 1>), dim3(GB_M), dim3(256), 0, stream,
                       Wdst_bf, feat_bf, b_dst, (const ushort*)nullptr, h_dst_bf);
    hipLaunchKernelGGL(attn_logits_kernel, dim3(GB_N4), dim3(256), 0, stream,
                       feat_src, W_attn_src, W_attn_dst, a_src_b, a_dst_b);

    // edge scores + softmax (unnormalized exp + zinv)
    hipLaunchKernelGGL(edge_score_kernel, dim3(GB_E), dim3(256), 0, stream,
                       feat_edge, edge_src, edge_dst, a_src_b, a_dst_b, W_attn_edge, eb);
    hipLaunchKernelGGL(softmax_kernel, dim3(GB_N4), dim3(256), 0, stream,
                       offsets, edge_ids, eb, zinv);

    // aggregation (bf16 gather, normalize by zinv, bf16 out into feat_bf region)
    hipLaunchKernelGGL(aggregate_kernel, dim3(GB_N4), dim3(256), 0, stream,
                       offsets, edge_ids, edge_src, eb, zinv, h_src_bf, agg_bf);

    // ngnn + relu + residual -> fp32 out
    hipLaunchKernelGGL((mfma_gemm<HF, 2>), dim3(GB_M), dim3(256), 0, stream,
                       Wngnn_bf, agg_bf, b_ngnn, h_dst_bf, out);
}

// Round 3
// 550.846 us; speedup vs baseline: 1.8763x; 1.4143x over previous
//
#include <hip/hip_runtime.h>
#include <hip/hip_bf16.h>
#include <math.h>

#define NN 100000
#define EE 1600000
#define DD 256
#define DEE 8
#define HF 128           // H*F
#define NEG_SLOPE 0.2f
#define NBUCK 196        // ceil(NN/512) coarse dst-buckets (512 nodes each)
#define P1_EPB 4096      // edges per block in bucket_scatter

typedef __bf16 bf16x8 __attribute__((ext_vector_type(8)));
typedef float  f32x4  __attribute__((ext_vector_type(4)));

__device__ inline ushort f2bf(float f) {          // round-to-nearest-even
    uint32_t x = __builtin_bit_cast(uint32_t, f);
    x += 0x7fffu + ((x >> 16) & 1u);
    return (ushort)(x >> 16);
}
__device__ inline float bf2f(ushort u) {
    uint32_t x = ((uint32_t)u) << 16;
    return __builtin_bit_cast(float, x);
}
__device__ inline float u2f(uint u) { return __builtin_bit_cast(float, u); }
__device__ inline uint f2u(float f) { return __builtin_bit_cast(uint, f); }

__device__ inline void load_lds16(const void* g, void* l) {
    __builtin_amdgcn_global_load_lds(
        (const __attribute__((address_space(1))) void*)g,
        (__attribute__((address_space(3))) void*)l, 16, 0, 0);
}

// ---------------------------------------------------------------------------
// fp32 -> bf16 cast (weights only)
// ---------------------------------------------------------------------------
__global__ __launch_bounds__(256) void f2bf_kernel(
    const float* __restrict__ in, ushort* __restrict__ out, int n)
{
    int i = (blockIdx.x * 256 + threadIdx.x) * 4;
    if (i + 3 < n) {
        float4 v = *(const float4*)(in + i);
        ushort4 o;
        o.x = f2bf(v.x); o.y = f2bf(v.y); o.z = f2bf(v.z); o.w = f2bf(v.w);
        *(ushort4*)(out + i) = o;
    } else {
        for (int c = 0; c < 4 && i + c < n; ++c) out[i + c] = f2bf(in[i + c]);
    }
}

// ---------------------------------------------------------------------------
// MFMA GEMM: D[f][node] = sum_k Wb[f][k] * Xb[node][k]   (both bf16 [rows][K])
// MODE 0: bf16 out; MODE 1: bf16 out + bias; MODE 2: fp32 relu(acc+bias)+resid
// ---------------------------------------------------------------------------
template<int K, int MODE>
__global__ __launch_bounds__(256) void mfma_gemm(
    const ushort* __restrict__ Wb,     // [128][K]
    const ushort* __restrict__ Xb,     // [NN][K]
    const float*  __restrict__ bias,
    const ushort* __restrict__ resid,  // [NN][128] bf16 (MODE 2)
    void* __restrict__ outp)
{
    __shared__ ushort As[128 * 32];
    __shared__ ushort Bs[128 * 32];

    const int tid  = threadIdx.x;
    const int lane = tid & 63, wv = tid >> 6;
    const int wm = wv >> 1, wn = wv & 1;
    const int r = lane & 15, quad = lane >> 4;
    const int m0 = blockIdx.x * 128;

    f32x4 acc[4][4] = {};

    for (int k0 = 0; k0 < K; k0 += 32) {
#pragma unroll
        for (int t = 0; t < 2; ++t) {
            int is  = wv + t * 4;
            int row = is * 16 + (lane >> 2);
            int ko  = k0 + (lane & 3) * 8;
            load_lds16(Wb + (size_t)row * K + ko, &As[is * 512]);
            int gm = m0 + row; gm = gm < NN ? gm : NN - 1;
            load_lds16(Xb + (size_t)gm * K + ko, &Bs[is * 512]);
        }
        __syncthreads();
        bf16x8 a[4], b[4];
#pragma unroll
        for (int i = 0; i < 4; ++i) {
            a[i] = __builtin_bit_cast(bf16x8,
                   *(const f32x4*)&As[(wm * 64 + i * 16 + r) * 32 + quad * 8]);
            b[i] = __builtin_bit_cast(bf16x8,
                   *(const f32x4*)&Bs[(wn * 64 + i * 16 + r) * 32 + quad * 8]);
        }
#pragma unroll
        for (int i = 0; i < 4; ++i)
#pragma unroll
            for (int j = 0; j < 4; ++j)
                acc[i][j] = __builtin_amdgcn_mfma_f32_16x16x32_bf16(
                    a[i], b[j], acc[i][j], 0, 0, 0);
        __syncthreads();
    }

#pragma unroll
    for (int i = 0; i < 4; ++i) {
        int fbase = wm * 64 + i * 16 + quad * 4;
        float4 bv = make_float4(0.f, 0.f, 0.f, 0.f);
        if (MODE >= 1) bv = *(const float4*)(bias + fbase);
#pragma unroll
        for (int j = 0; j < 4; ++j) {
            int node = m0 + wn * 64 + j * 16 + r;
            if (node >= NN) continue;
            f32x4 v = acc[i][j];
            if (MODE >= 1) { v[0] += bv.x; v[1] += bv.y; v[2] += bv.z; v[3] += bv.w; }
            if (MODE == 2) {
                ushort4 rs = *(const ushort4*)(resid + (size_t)node * HF + fbase);
                float4 o;
                o.x = fmaxf(v[0], 0.f) + bf2f(rs.x);
                o.y = fmaxf(v[1], 0.f) + bf2f(rs.y);
                o.z = fmaxf(v[2], 0.f) + bf2f(rs.z);
                o.w = fmaxf(v[3], 0.f) + bf2f(rs.w);
                *(float4*)((float*)outp + (size_t)node * HF + fbase) = o;
            } else {
                ushort4 o;
                o.x = f2bf(v[0]); o.y = f2bf(v[1]); o.z = f2bf(v[2]); o.w = f2bf(v[3]);
                *(ushort4*)((ushort*)outp + (size_t)node * HF + fbase) = o;
            }
        }
    }
}

// ---------------------------------------------------------------------------
// attn logits + fused feat fp32->bf16. One wave per node.
// ---------------------------------------------------------------------------
__global__ __launch_bounds__(256) void attn_logits_kernel(
    const float* __restrict__ feat,
    const float* __restrict__ Was, const float* __restrict__ Wad,
    float* __restrict__ a_src, float* __restrict__ a_dst,
    ushort* __restrict__ feat_bf)
{
    int wave = threadIdx.x >> 6, lane = threadIdx.x & 63;
    int node = blockIdx.x * 4 + wave;
    if (node >= NN) return;
    float4 f = *(const float4*)(feat + (size_t)node * DD + lane * 4);
    ushort4 fb;
    fb.x = f2bf(f.x); fb.y = f2bf(f.y); fb.z = f2bf(f.z); fb.w = f2bf(f.w);
    *(ushort4*)(feat_bf + (size_t)node * DD + lane * 4) = fb;

    float4 w0 = *(const float4*)(Was + 0 * DD + lane * 4);
    float4 w1 = *(const float4*)(Was + 1 * DD + lane * 4);
    float4 w2 = *(const float4*)(Wad + 0 * DD + lane * 4);
    float4 w3 = *(const float4*)(Wad + 1 * DD + lane * 4);
    float p0 = f.x * w0.x + f.y * w0.y + f.z * w0.z + f.w * w0.w;
    float p1 = f.x * w1.x + f.y * w1.y + f.z * w1.z + f.w * w1.w;
    float p2 = f.x * w2.x + f.y * w2.y + f.z * w2.z + f.w * w2.w;
    float p3 = f.x * w3.x + f.y * w3.y + f.z * w3.z + f.w * w3.w;
#pragma unroll
    for (int o = 32; o > 0; o >>= 1) {
        p0 += __shfl_xor(p0, o);
        p1 += __shfl_xor(p1, o);
        p2 += __shfl_xor(p2, o);
        p3 += __shfl_xor(p3, o);
    }
    if (lane == 0) {
        a_src[node * 2 + 0] = p0; a_src[node * 2 + 1] = p1;
        a_dst[node * 2 + 0] = p2; a_dst[node * 2 + 1] = p3;
    }
}

// ---------------------------------------------------------------------------
// CSR degree histogram + scan
// ---------------------------------------------------------------------------
__global__ __launch_bounds__(256) void hist_kernel(
    const int* __restrict__ edge_dst, int* __restrict__ deg)
{
    int i = blockIdx.x * 256 + threadIdx.x;
    if (i < EE) atomicAdd(&deg[edge_dst[i]], 1);
}

#define SCAN_ELEMS 1024
__global__ __launch_bounds__(256) void scan1_kernel(
    const int* __restrict__ deg, int* __restrict__ offsets, int* __restrict__ blockSums)
{
    __shared__ int sd[256];
    int tid = threadIdx.x;
    int base = blockIdx.x * SCAN_ELEMS + tid * 4;
    int v[4];
#pragma unroll
    for (int c = 0; c < 4; ++c) v[c] = (base + c < NN) ? deg[base + c] : 0;
    int tsum = v[0] + v[1] + v[2] + v[3];
    sd[tid] = tsum;
    __syncthreads();
    for (int o = 1; o < 256; o <<= 1) {
        int x = (tid >= o) ? sd[tid - o] : 0;
        __syncthreads();
        sd[tid] += x;
        __syncthreads();
    }
    int excl = sd[tid] - tsum;
    int run = excl;
#pragma unroll
    for (int c = 0; c < 4; ++c) {
        if (base + c < NN) offsets[base + c] = run;
        run += v[c];
    }
    if (tid == 255) blockSums[blockIdx.x] = sd[255];
}

__global__ __launch_bounds__(128) void scan2_kernel(int* __restrict__ blockSums, int nb)
{
    __shared__ int sd[128];
    int tid = threadIdx.x;
    int tv = (tid < nb) ? blockSums[tid] : 0;
    sd[tid] = tv;
    __syncthreads();
    for (int o = 1; o < 128; o <<= 1) {
        int x = (tid >= o) ? sd[tid - o] : 0;
        __syncthreads();
        sd[tid] += x;
        __syncthreads();
    }
    if (tid < nb) blockSums[tid] = sd[tid] - tv;
}

__global__ __launch_bounds__(256) void scan3_kernel(
    int* __restrict__ offsets, const int* __restrict__ blockSums)
{
    int tid = threadIdx.x;
    int base = blockIdx.x * SCAN_ELEMS + tid * 4;
    int add = blockSums[blockIdx.x];
#pragma unroll
    for (int c = 0; c < 4; ++c)
        if (base + c < NN) offsets[base + c] += add;
    if (blockIdx.x == 0 && tid == 0) offsets[NN] = EE;
}

// bucket cursor init: bcur[b] = offsets[b*512]
__global__ __launch_bounds__(256) void binit_kernel(
    const int* __restrict__ offsets, int* __restrict__ bcur)
{
    int t = threadIdx.x;
    if (t < NBUCK) bcur[t] = offsets[t * 512];
}

// ---------------------------------------------------------------------------
// Phase 1: fused edge-score + coarse bucket scatter.
// Writes (src, dst, s0, s1) uint4 items into per-block contiguous ranges of
// the staging buffer, grouped by dst>>9 bucket (dense line writes).
// ---------------------------------------------------------------------------
__global__ __launch_bounds__(256) void bucket_scatter_kernel(
    const int* __restrict__ edge_src, const int* __restrict__ edge_dst,
    const float* __restrict__ feat_edge,
    const float* __restrict__ a_src, const float* __restrict__ a_dst,
    const float* __restrict__ Wae,
    int* __restrict__ bcur, uint4* __restrict__ staging)
{
    __shared__ int cnt[256];
    __shared__ int basearr[256];
    __shared__ int run[256];
    const int tid = threadIdx.x;
    const int b0 = blockIdx.x * P1_EPB;

    cnt[tid] = 0;
    __syncthreads();
#pragma unroll
    for (int j = 0; j < P1_EPB / 256; ++j) {
        int i = b0 + j * 256 + tid;
        if (i < EE) atomicAdd(&cnt[edge_dst[i] >> 9], 1);
    }
    __syncthreads();
    if (tid < NBUCK) {
        int c = cnt[tid];
        basearr[tid] = c ? atomicAdd(&bcur[tid], c) : 0;
    }
    run[tid] = 0;
    __syncthreads();

    float4 w00 = ((const float4*)Wae)[0], w01 = ((const float4*)Wae)[1];
    float4 w10 = ((const float4*)Wae)[2], w11 = ((const float4*)Wae)[3];

#pragma unroll
    for (int j = 0; j < P1_EPB / 256; ++j) {
        int i = b0 + j * 256 + tid;
        if (i >= EE) continue;
        int s = edge_src[i], d = edge_dst[i];
        float4 e0 = ((const float4*)feat_edge)[i * 2 + 0];
        float4 e1 = ((const float4*)feat_edge)[i * 2 + 1];
        float ae0 = e0.x*w00.x + e0.y*w00.y + e0.z*w00.z + e0.w*w00.w
                  + e1.x*w01.x + e1.y*w01.y + e1.z*w01.z + e1.w*w01.w;
        float ae1 = e0.x*w10.x + e0.y*w10.y + e0.z*w10.z + e0.w*w10.w
                  + e1.x*w11.x + e1.y*w11.y + e1.z*w11.z + e1.w*w11.w;
        float v0 = a_src[s * 2 + 0] + a_dst[d * 2 + 0] + ae0;
        float v1 = a_src[s * 2 + 1] + a_dst[d * 2 + 1] + ae1;
        v0 = (v0 >= 0.f) ? v0 : NEG_SLOPE * v0;
        v1 = (v1 >= 0.f) ? v1 : NEG_SLOPE * v1;
        int bk = d >> 9;
        int ofs = atomicAdd(&run[bk], 1);
        staging[basearr[bk] + ofs] = make_uint4((uint)s, (uint)d, f2u(v0), f2u(v1));
    }
}

// ---------------------------------------------------------------------------
// Phase 2: fine scatter within bucket. LDS cursors; writes confined to the
// bucket's CSR region (L2-absorbed line amplification).
// ---------------------------------------------------------------------------
__global__ __launch_bounds__(256) void fine_scatter_kernel(
    const int* __restrict__ offsets,
    const uint4* __restrict__ staging, uint4* __restrict__ pairs)
{
    __shared__ int cur[512];
    const int tid = threadIdx.x;
    const int nb0 = blockIdx.x * 512;
    const int ncnt = (NN - nb0 < 512) ? (NN - nb0) : 512;
    for (int i = tid; i < ncnt; i += 256) cur[i] = offsets[nb0 + i];
    __syncthreads();
    const int lo = offsets[nb0];
    const int hi = offsets[nb0 + ncnt];
    for (int j = lo + tid; j < hi; j += 256) {
        uint4 it = staging[j];
        int n = (int)it.y - nb0;
        int pos = atomicAdd(&cur[n], 1);
        pairs[pos] = it;
    }
}

// ---------------------------------------------------------------------------
// Fused edge-softmax + aggregation. One wave per dst node.
// pairs[j] = (src, dst, s0, s1) in CSR order.
// ---------------------------------------------------------------------------
__global__ __launch_bounds__(256) void aggregate_fused(
    const int* __restrict__ offsets,
    const uint4* __restrict__ pairs,
    const ushort* __restrict__ hsrc,
    ushort* __restrict__ agg)
{
    int wave = threadIdx.x >> 6, lane = threadIdx.x & 63;
    int node = blockIdx.x * 4 + wave;
    if (node >= NN) return;
    int off = offsets[node], end = offsets[node + 1];
    int n = end - off;
    uint* aggw = (uint*)agg;
    if (n <= 0) { aggw[(size_t)node * 64 + lane] = 0; return; }
    const uint* h2 = (const uint*)hsrc;
    int hh = lane >> 5;

    float acc0a = 0.f, acc1a = 0.f, acc0b = 0.f, acc1b = 0.f;
    float zi0, zi1;

    if (n <= 64) {
        uint4 pr = (lane < n) ? pairs[off + lane]
                              : make_uint4(0u, 0u, 0xff800000u, 0xff800000u);
        float s0 = u2f(pr.z), s1 = u2f(pr.w);
        float m0 = s0, m1 = s1;
#pragma unroll
        for (int o = 32; o > 0; o >>= 1) {
            m0 = fmaxf(m0, __shfl_xor(m0, o));
            m1 = fmaxf(m1, __shfl_xor(m1, o));
        }
        float ex0 = (lane < n) ? __expf(s0 - m0) : 0.f;
        float ex1 = (lane < n) ? __expf(s1 - m1) : 0.f;
        float z0 = ex0, z1 = ex1;
#pragma unroll
        for (int o = 32; o > 0; o >>= 1) {
            z0 += __shfl_xor(z0, o);
            z1 += __shfl_xor(z1, o);
        }
        zi0 = 1.f / z0; zi1 = 1.f / z1;
        int srcu = (int)pr.x;
        int k = 0;
        for (; k + 1 < n; k += 2) {
            int   sA = __shfl(srcu, k),     sB = __shfl(srcu, k + 1);
            float eA0 = __shfl(ex0, k),     eB0 = __shfl(ex0, k + 1);
            float eA1 = __shfl(ex1, k),     eB1 = __shfl(ex1, k + 1);
            uint pA = h2[(size_t)sA * 64 + lane];
            uint pB = h2[(size_t)sB * 64 + lane];
            float wA = hh ? eA1 : eA0;
            float wB = hh ? eB1 : eB0;
            acc0a = fmaf(wA, bf2f((ushort)(pA & 0xffff)), acc0a);
            acc1a = fmaf(wA, bf2f((ushort)(pA >> 16)),    acc1a);
            acc0b = fmaf(wB, bf2f((ushort)(pB & 0xffff)), acc0b);
            acc1b = fmaf(wB, bf2f((ushort)(pB >> 16)),    acc1b);
        }
        if (k < n) {
            int   sA = __shfl(srcu, k);
            float eA0 = __shfl(ex0, k), eA1 = __shfl(ex1, k);
            uint pA = h2[(size_t)sA * 64 + lane];
            float wA = hh ? eA1 : eA0;
            acc0a = fmaf(wA, bf2f((ushort)(pA & 0xffff)), acc0a);
            acc1a = fmaf(wA, bf2f((ushort)(pA >> 16)),    acc1a);
        }
    } else {
        // general path (degree > 64): 3 coalesced passes over the segment
        float m0 = -INFINITY, m1 = -INFINITY;
        for (int c0 = 0; c0 < n; c0 += 64) {
            if (c0 + lane < n) {
                uint4 pr = pairs[off + c0 + lane];
                m0 = fmaxf(m0, u2f(pr.z));
                m1 = fmaxf(m1, u2f(pr.w));
            }
        }
#pragma unroll
        for (int o = 32; o > 0; o >>= 1) {
            m0 = fmaxf(m0, __shfl_xor(m0, o));
            m1 = fmaxf(m1, __shfl_xor(m1, o));
        }
        float z0 = 0.f, z1 = 0.f;
        for (int c0 = 0; c0 < n; c0 += 64) {
            if (c0 + lane < n) {
                uint4 pr = pairs[off + c0 + lane];
                z0 += __expf(u2f(pr.z) - m0);
                z1 += __expf(u2f(pr.w) - m1);
            }
        }
#pragma unroll
        for (int o = 32; o > 0; o >>= 1) {
            z0 += __shfl_xor(z0, o);
            z1 += __shfl_xor(z1, o);
        }
        zi0 = 1.f / z0; zi1 = 1.f / z1;
        for (int c0 = 0; c0 < n; c0 += 64) {
            int cn = n - c0; if (cn > 64) cn = 64;
            uint4 pr = (lane < cn) ? pairs[off + c0 + lane]
                                   : make_uint4(0u, 0u, 0u, 0u);
            float ex0 = (lane < cn) ? __expf(u2f(pr.z) - m0) : 0.f;
            float ex1 = (lane < cn) ? __expf(u2f(pr.w) - m1) : 0.f;
            int srcu = (int)pr.x;
            for (int k = 0; k < cn; ++k) {
                int   sA = __shfl(srcu, k);
                float eA0 = __shfl(ex0, k), eA1 = __shfl(ex1, k);
                uint pA = h2[(size_t)sA * 64 + lane];
                float wA = hh ? eA1 : eA0;
                acc0a = fmaf(wA, bf2f((ushort)(pA & 0xffff)), acc0a);
                acc1a = fmaf(wA, bf2f((ushort)(pA >> 16)),    acc1a);
            }
        }
    }

    float zi = hh ? zi1 : zi0;
    float r0 = (acc0a + acc0b) * zi;
    float r1 = (acc1a + acc1b) * zi;
    aggw[(size_t)node * 64 + lane] = ((uint)f2bf(r1) << 16) | (uint)f2bf(r0);
}

// ---------------------------------------------------------------------------
extern "C" void kernel_launch(void* const* d_in, const int* in_sizes, int n_in,
                              void* d_out, int out_size, void* d_ws, size_t ws_size,
                              hipStream_t stream) {
    (void)in_sizes; (void)n_in; (void)out_size; (void)ws_size;
    const float* feat_src  = (const float*)d_in[0];
    const float* feat_edge = (const float*)d_in[1];
    const int*   edge_src  = (const int*)d_in[2];
    const int*   edge_dst  = (const int*)d_in[3];
    const float* W_src     = (const float*)d_in[4];
    const float* W_dst     = (const float*)d_in[5];
    const float* b_dst     = (const float*)d_in[6];
    const float* W_attn_src  = (const float*)d_in[7];
    const float* W_attn_dst  = (const float*)d_in[8];
    const float* W_attn_edge = (const float*)d_in[9];
    const float* W_ngnn    = (const float*)d_in[10];
    const float* b_ngnn    = (const float*)d_in[11];
    float* out = (float*)d_out;

    char* base = (char*)d_ws;
    size_t off = 0;
    auto take = [&](size_t bytes) -> void* {
        void* p = base + off;
        off = (off + bytes + 511) & ~(size_t)511;
        return p;
    };
    ushort* feat_bf  = (ushort*)take((size_t)NN * DD * 2);    // 51.2 MB
    ushort* h_src_bf = (ushort*)take((size_t)NN * HF * 2);    // 25.6 MB
    uint4*  staging  = (uint4*)take((size_t)EE * 16);         // 25.6 MB
    uint4*  pairs    = (uint4*)take((size_t)EE * 16);         // 25.6 MB
    float*  a_src_b  = (float*)take((size_t)NN * 2 * 4);
    float*  a_dst_b  = (float*)take((size_t)NN * 2 * 4);
    int*    deg      = (int*)take((size_t)NN * 4);
    int*    offsets  = (int*)take((size_t)(NN + 1) * 4);
    int*    bcur     = (int*)take((size_t)NBUCK * 4);
    int*    blockSums= (int*)take(512);
    ushort* Wsrc_bf  = (ushort*)take((size_t)HF * DD * 2);
    ushort* Wdst_bf  = (ushort*)take((size_t)HF * DD * 2);
    ushort* Wngnn_bf = (ushort*)take((size_t)HF * HF * 2);
    ushort* h_dst_bf = (ushort*)staging;   // staging dead after fine_scatter
    ushort* agg_bf   = feat_bf;            // feat_bf dead after proj GEMMs

    const int NB_SCAN = (NN + SCAN_ELEMS - 1) / SCAN_ELEMS;   // 98
    const int GB_E  = (EE + 255) / 256;                       // 6250
    const int GB_M  = (NN + 127) / 128;                       // 782
    const int GB_N4 = (NN + 3) / 4;                           // 25000
    const int GB_P1 = (EE + P1_EPB - 1) / P1_EPB;             // 391

    // CSR offsets
    hipMemsetAsync(deg, 0, (size_t)NN * 4, stream);
    hipLaunchKernelGGL(hist_kernel, dim3(GB_E), dim3(256), 0, stream, edge_dst, deg);
    hipLaunchKernelGGL(scan1_kernel, dim3(NB_SCAN), dim3(256), 0, stream, deg, offsets, blockSums);
    hipLaunchKernelGGL(scan2_kernel, dim3(1), dim3(128), 0, stream, blockSums, NB_SCAN);
    hipLaunchKernelGGL(scan3_kernel, dim3(NB_SCAN), dim3(256), 0, stream, offsets, blockSums);
    hipLaunchKernelGGL(binit_kernel, dim3(1), dim3(256), 0, stream, offsets, bcur);

    // attn logits + feat->bf16 (fused)
    hipLaunchKernelGGL(attn_logits_kernel, dim3(GB_N4), dim3(256), 0, stream,
                       feat_src, W_attn_src, W_attn_dst, a_src_b, a_dst_b, feat_bf);

    // weight conversions
    hipLaunchKernelGGL(f2bf_kernel, dim3((HF * DD / 4 + 255) / 256), dim3(256), 0, stream,
                       W_src, Wsrc_bf, HF * DD);
    hipLaunchKernelGGL(f2bf_kernel, dim3((HF * DD / 4 + 255) / 256), dim3(256), 0, stream,
                       W_dst, Wdst_bf, HF * DD);
    hipLaunchKernelGGL(f2bf_kernel, dim3((HF * HF / 4 + 255) / 256), dim3(256), 0, stream,
                       W_ngnn, Wngnn_bf, HF * HF);

    // edge scores + 2-phase counting sort into CSR order
    hipLaunchKernelGGL(bucket_scatter_kernel, dim3(GB_P1), dim3(256), 0, stream,
                       edge_src, edge_dst, feat_edge, a_src_b, a_dst_b, W_attn_edge,
                       bcur, staging);
    hipLaunchKernelGGL(fine_scatter_kernel, dim3(NBUCK), dim3(256), 0, stream,
                       offsets, staging, pairs);

    // projections (MFMA)
    hipLaunchKernelGGL((mfma_gemm<DD, 0>), dim3(GB_M), dim3(256), 0, stream,
                       Wsrc_bf, feat_bf, (const float*)nullptr, (const ushort*)nullptr, h_src_bf);
    hipLaunchKernelGGL((mfma_gemm<DD, 1>), dim3(GB_M), dim3(256), 0, stream,
                       Wdst_bf, feat_bf, b_dst, (const ushort*)nullptr, h_dst_bf);

    // fused softmax + aggregation
    hipLaunchKernelGGL(aggregate_fused, dim3(GB_N4), dim3(256), 0, stream,
                       offsets, pairs, h_src_bf, agg_bf);

    // ngnn + relu + residual -> fp32 out
    hipLaunchKernelGGL((mfma_gemm<HF, 2>), dim3(GB_M), dim3(256), 0, stream,
                       Wngnn_bf, agg_bf, b_ngnn, h_dst_bf, out);
}

// Round 4
// 521.430 us; speedup vs baseline: 1.9822x; 1.0564x over previous
//
#include <hip/hip_runtime.h>
#include <hip/hip_bf16.h>
#include <math.h>

#define NN 100000
#define EE 1600000
#define DD 256
#define DEE 8
#define HF 128           // H*F
#define NEG_SLOPE 0.2f
#define NBUCK 196        // ceil(NN/512) coarse dst-buckets (512 nodes each)
#define P1_EPB 1024      // edges per block in bucket_scatter (1563 blocks -> ~70% occ)

typedef __bf16 bf16x8 __attribute__((ext_vector_type(8)));
typedef float  f32x4  __attribute__((ext_vector_type(4)));

__device__ inline ushort f2bf(float f) {          // round-to-nearest-even
    uint32_t x = __builtin_bit_cast(uint32_t, f);
    x += 0x7fffu + ((x >> 16) & 1u);
    return (ushort)(x >> 16);
}
__device__ inline float bf2f(ushort u) {
    uint32_t x = ((uint32_t)u) << 16;
    return __builtin_bit_cast(float, x);
}
__device__ inline float u2f(uint u) { return __builtin_bit_cast(float, u); }
__device__ inline uint f2u(float f) { return __builtin_bit_cast(uint, f); }
__device__ inline float lo_bf(uint p) { return __builtin_bit_cast(float, p << 16); }
__device__ inline float hi_bf(uint p) { return __builtin_bit_cast(float, p & 0xffff0000u); }

__device__ inline void load_lds16(const void* g, void* l) {
    __builtin_amdgcn_global_load_lds(
        (const __attribute__((address_space(1))) void*)g,
        (__attribute__((address_space(3))) void*)l, 16, 0, 0);
}

// ---------------------------------------------------------------------------
// fp32 -> bf16 for the 3 weight matrices in one launch
// ---------------------------------------------------------------------------
__global__ __launch_bounds__(256) void f2bf3_kernel(
    const float* __restrict__ wa, const float* __restrict__ wb,
    const float* __restrict__ wc,
    ushort* __restrict__ oa, ushort* __restrict__ ob, ushort* __restrict__ oc)
{
    int i = (blockIdx.x * 256 + threadIdx.x) * 4;
    const int na = HF * DD, nb2 = 2 * HF * DD, nc3 = 2 * HF * DD + HF * HF;
    const float* src; ushort* dst; int o;
    if (i < na)       { src = wa; dst = oa; o = i; }
    else if (i < nb2) { src = wb; dst = ob; o = i - na; }
    else if (i < nc3) { src = wc; dst = oc; o = i - nb2; }
    else return;
    float4 v = *(const float4*)(src + o);
    ushort4 u;
    u.x = f2bf(v.x); u.y = f2bf(v.y); u.z = f2bf(v.z); u.w = f2bf(v.w);
    *(ushort4*)(dst + o) = u;
}

// ---------------------------------------------------------------------------
// Dual MFMA GEMM: out0[node][f] = sum_k W0[f][k]*X[node][k]
//                 out1[node][f] = same with W1, + bias1
// 64-node tile, both W slabs staged; feat read from HBM ONCE total.
// ---------------------------------------------------------------------------
template<int K>
__global__ __launch_bounds__(256) void mfma_gemm_dual(
    const ushort* __restrict__ W0,     // [128][K]
    const ushort* __restrict__ W1,     // [128][K]
    const ushort* __restrict__ Xb,     // [NN][K]
    const float*  __restrict__ bias1,  // [128]
    ushort* __restrict__ out0, ushort* __restrict__ out1)
{
    __shared__ ushort As[2][128 * 32];
    __shared__ ushort Bs[64 * 32];

    const int tid  = threadIdx.x;
    const int lane = tid & 63, wv = tid >> 6;
    const int wm = wv >> 1, wn = wv & 1;
    const int r = lane & 15, quad = lane >> 4;
    const int m0 = blockIdx.x * 64;

    f32x4 acc[2][4][2] = {};

    for (int k0 = 0; k0 < K; k0 += 32) {
#pragma unroll
        for (int t = 0; t < 2; ++t) {
            int is  = wv + t * 4;
            int row = is * 16 + (lane >> 2);
            int ko  = k0 + (lane & 3) * 8;
            load_lds16(W0 + (size_t)row * K + ko, &As[0][is * 512]);
            load_lds16(W1 + (size_t)row * K + ko, &As[1][is * 512]);
        }
        {
            int is  = wv;
            int row = is * 16 + (lane >> 2);
            int ko  = k0 + (lane & 3) * 8;
            int gm = m0 + row; gm = gm < NN ? gm : NN - 1;
            load_lds16(Xb + (size_t)gm * K + ko, &Bs[is * 512]);
        }
        __syncthreads();
        bf16x8 a[2][4], b[2];
#pragma unroll
        for (int i = 0; i < 4; ++i) {
            a[0][i] = __builtin_bit_cast(bf16x8,
                      *(const f32x4*)&As[0][(wm * 64 + i * 16 + r) * 32 + quad * 8]);
            a[1][i] = __builtin_bit_cast(bf16x8,
                      *(const f32x4*)&As[1][(wm * 64 + i * 16 + r) * 32 + quad * 8]);
        }
#pragma unroll
        for (int j = 0; j < 2; ++j)
            b[j] = __builtin_bit_cast(bf16x8,
                   *(const f32x4*)&Bs[(wn * 32 + j * 16 + r) * 32 + quad * 8]);
#pragma unroll
        for (int s = 0; s < 2; ++s)
#pragma unroll
            for (int i = 0; i < 4; ++i)
#pragma unroll
                for (int j = 0; j < 2; ++j)
                    acc[s][i][j] = __builtin_amdgcn_mfma_f32_16x16x32_bf16(
                        a[s][i], b[j], acc[s][i][j], 0, 0, 0);
        __syncthreads();
    }

#pragma unroll
    for (int s = 0; s < 2; ++s) {
        ushort* outp = s ? out1 : out0;
#pragma unroll
        for (int i = 0; i < 4; ++i) {
            int fbase = wm * 64 + i * 16 + quad * 4;
            float4 bv = make_float4(0.f, 0.f, 0.f, 0.f);
            if (s == 1) bv = *(const float4*)(bias1 + fbase);
#pragma unroll
            for (int j = 0; j < 2; ++j) {
                int node = m0 + wn * 32 + j * 16 + r;
                if (node >= NN) continue;
                f32x4 v = acc[s][i][j];
                v[0] += bv.x; v[1] += bv.y; v[2] += bv.z; v[3] += bv.w;
                ushort4 o;
                o.x = f2bf(v[0]); o.y = f2bf(v[1]); o.z = f2bf(v[2]); o.w = f2bf(v[3]);
                *(ushort4*)(outp + (size_t)node * HF + fbase) = o;
            }
        }
    }
}

// ---------------------------------------------------------------------------
// ngnn GEMM (K=128): fp32 out[node][f] = relu(acc+bias) + bf2f(resid)
// ---------------------------------------------------------------------------
template<int K>
__global__ __launch_bounds__(256) void mfma_gemm_ngnn(
    const ushort* __restrict__ Wb,
    const ushort* __restrict__ Xb,
    const float*  __restrict__ bias,
    const ushort* __restrict__ resid,
    float* __restrict__ outp)
{
    __shared__ ushort As[128 * 32];
    __shared__ ushort Bs[128 * 32];

    const int tid  = threadIdx.x;
    const int lane = tid & 63, wv = tid >> 6;
    const int wm = wv >> 1, wn = wv & 1;
    const int r = lane & 15, quad = lane >> 4;
    const int m0 = blockIdx.x * 128;

    f32x4 acc[4][4] = {};

    for (int k0 = 0; k0 < K; k0 += 32) {
#pragma unroll
        for (int t = 0; t < 2; ++t) {
            int is  = wv + t * 4;
            int row = is * 16 + (lane >> 2);
            int ko  = k0 + (lane & 3) * 8;
            load_lds16(Wb + (size_t)row * K + ko, &As[is * 512]);
            int gm = m0 + row; gm = gm < NN ? gm : NN - 1;
            load_lds16(Xb + (size_t)gm * K + ko, &Bs[is * 512]);
        }
        __syncthreads();
        bf16x8 a[4], b[4];
#pragma unroll
        for (int i = 0; i < 4; ++i) {
            a[i] = __builtin_bit_cast(bf16x8,
                   *(const f32x4*)&As[(wm * 64 + i * 16 + r) * 32 + quad * 8]);
            b[i] = __builtin_bit_cast(bf16x8,
                   *(const f32x4*)&Bs[(wn * 64 + i * 16 + r) * 32 + quad * 8]);
        }
#pragma unroll
        for (int i = 0; i < 4; ++i)
#pragma unroll
            for (int j = 0; j < 4; ++j)
                acc[i][j] = __builtin_amdgcn_mfma_f32_16x16x32_bf16(
                    a[i], b[j], acc[i][j], 0, 0, 0);
        __syncthreads();
    }

#pragma unroll
    for (int i = 0; i < 4; ++i) {
        int fbase = wm * 64 + i * 16 + quad * 4;
        float4 bv = *(const float4*)(bias + fbase);
#pragma unroll
        for (int j = 0; j < 4; ++j) {
            int node = m0 + wn * 64 + j * 16 + r;
            if (node >= NN) continue;
            f32x4 v = acc[i][j];
            ushort4 rs = *(const ushort4*)(resid + (size_t)node * HF + fbase);
            float4 o;
            o.x = fmaxf(v[0] + bv.x, 0.f) + bf2f(rs.x);
            o.y = fmaxf(v[1] + bv.y, 0.f) + bf2f(rs.y);
            o.z = fmaxf(v[2] + bv.z, 0.f) + bf2f(rs.z);
            o.w = fmaxf(v[3] + bv.w, 0.f) + bf2f(rs.w);
            *(float4*)(outp + (size_t)node * HF + fbase) = o;
        }
    }
}

// ---------------------------------------------------------------------------
// attn logits + fused feat fp32->bf16. One wave per node.
// ---------------------------------------------------------------------------
__global__ __launch_bounds__(256) void attn_logits_kernel(
    const float* __restrict__ feat,
    const float* __restrict__ Was, const float* __restrict__ Wad,
    float* __restrict__ a_src, float* __restrict__ a_dst,
    ushort* __restrict__ feat_bf)
{
    int wave = threadIdx.x >> 6, lane = threadIdx.x & 63;
    int node = blockIdx.x * 4 + wave;
    if (node >= NN) return;
    float4 f = *(const float4*)(feat + (size_t)node * DD + lane * 4);
    ushort4 fb;
    fb.x = f2bf(f.x); fb.y = f2bf(f.y); fb.z = f2bf(f.z); fb.w = f2bf(f.w);
    *(ushort4*)(feat_bf + (size_t)node * DD + lane * 4) = fb;

    float4 w0 = *(const float4*)(Was + 0 * DD + lane * 4);
    float4 w1 = *(const float4*)(Was + 1 * DD + lane * 4);
    float4 w2 = *(const float4*)(Wad + 0 * DD + lane * 4);
    float4 w3 = *(const float4*)(Wad + 1 * DD + lane * 4);
    float p0 = f.x * w0.x + f.y * w0.y + f.z * w0.z + f.w * w0.w;
    float p1 = f.x * w1.x + f.y * w1.y + f.z * w1.z + f.w * w1.w;
    float p2 = f.x * w2.x + f.y * w2.y + f.z * w2.z + f.w * w2.w;
    float p3 = f.x * w3.x + f.y * w3.y + f.z * w3.z + f.w * w3.w;
#pragma unroll
    for (int o = 32; o > 0; o >>= 1) {
        p0 += __shfl_xor(p0, o);
        p1 += __shfl_xor(p1, o);
        p2 += __shfl_xor(p2, o);
        p3 += __shfl_xor(p3, o);
    }
    if (lane == 0) {
        a_src[node * 2 + 0] = p0; a_src[node * 2 + 1] = p1;
        a_dst[node * 2 + 0] = p2; a_dst[node * 2 + 1] = p3;
    }
}

// ---------------------------------------------------------------------------
// CSR degree histogram + scan
// ---------------------------------------------------------------------------
__global__ __launch_bounds__(256) void hist_kernel(
    const int* __restrict__ edge_dst, int* __restrict__ deg)
{
    int i = blockIdx.x * 256 + threadIdx.x;
    if (i < EE) atomicAdd(&deg[edge_dst[i]], 1);
}

#define SCAN_ELEMS 1024
__global__ __launch_bounds__(256) void scan1_kernel(
    const int* __restrict__ deg, int* __restrict__ offsets, int* __restrict__ blockSums)
{
    __shared__ int sd[256];
    int tid = threadIdx.x;
    int base = blockIdx.x * SCAN_ELEMS + tid * 4;
    int v[4];
#pragma unroll
    for (int c = 0; c < 4; ++c) v[c] = (base + c < NN) ? deg[base + c] : 0;
    int tsum = v[0] + v[1] + v[2] + v[3];
    sd[tid] = tsum;
    __syncthreads();
    for (int o = 1; o < 256; o <<= 1) {
        int x = (tid >= o) ? sd[tid - o] : 0;
        __syncthreads();
        sd[tid] += x;
        __syncthreads();
    }
    int excl = sd[tid] - tsum;
    int run = excl;
#pragma unroll
    for (int c = 0; c < 4; ++c) {
        if (base + c < NN) offsets[base + c] = run;
        run += v[c];
    }
    if (tid == 255) blockSums[blockIdx.x] = sd[255];
}

__global__ __launch_bounds__(128) void scan2_kernel(int* __restrict__ blockSums, int nb)
{
    __shared__ int sd[128];
    int tid = threadIdx.x;
    int tv = (tid < nb) ? blockSums[tid] : 0;
    sd[tid] = tv;
    __syncthreads();
    for (int o = 1; o < 128; o <<= 1) {
        int x = (tid >= o) ? sd[tid - o] : 0;
        __syncthreads();
        sd[tid] += x;
        __syncthreads();
    }
    if (tid < nb) blockSums[tid] = sd[tid] - tv;
}

// scan3 + bucket-cursor init fused
__global__ __launch_bounds__(256) void scan3_kernel(
    int* __restrict__ offsets, const int* __restrict__ blockSums,
    int* __restrict__ bcur)
{
    int tid = threadIdx.x;
    int base = blockIdx.x * SCAN_ELEMS + tid * 4;
    int add = blockSums[blockIdx.x];
#pragma unroll
    for (int c = 0; c < 4; ++c) {
        int idx = base + c;
        if (idx < NN) {
            int v = offsets[idx] + add;
            offsets[idx] = v;
            if ((idx & 511) == 0) bcur[idx >> 9] = v;
        }
    }
    if (blockIdx.x == 0 && tid == 0) offsets[NN] = EE;
}

// ---------------------------------------------------------------------------
// Phase 1: fused edge-score + coarse bucket scatter (1024 edges/block).
// ---------------------------------------------------------------------------
__global__ __launch_bounds__(256) void bucket_scatter_kernel(
    const int* __restrict__ edge_src, const int* __restrict__ edge_dst,
    const float* __restrict__ feat_edge,
    const float* __restrict__ a_src, const float* __restrict__ a_dst,
    const float* __restrict__ Wae,
    int* __restrict__ bcur, uint4* __restrict__ staging)
{
    __shared__ int cnt[256];
    __shared__ int basearr[256];
    __shared__ int run[256];
    const int tid = threadIdx.x;
    const int b0 = blockIdx.x * P1_EPB;

    cnt[tid] = 0;
    __syncthreads();
#pragma unroll
    for (int j = 0; j < P1_EPB / 256; ++j) {
        int i = b0 + j * 256 + tid;
        if (i < EE) atomicAdd(&cnt[edge_dst[i] >> 9], 1);
    }
    __syncthreads();
    if (tid < NBUCK) {
        int c = cnt[tid];
        basearr[tid] = c ? atomicAdd(&bcur[tid], c) : 0;
    }
    run[tid] = 0;
    __syncthreads();

    float4 w00 = ((const float4*)Wae)[0], w01 = ((const float4*)Wae)[1];
    float4 w10 = ((const float4*)Wae)[2], w11 = ((const float4*)Wae)[3];

#pragma unroll
    for (int j = 0; j < P1_EPB / 256; ++j) {
        int i = b0 + j * 256 + tid;
        if (i >= EE) continue;
        int s = edge_src[i], d = edge_dst[i];
        float4 e0 = ((const float4*)feat_edge)[i * 2 + 0];
        float4 e1 = ((const float4*)feat_edge)[i * 2 + 1];
        float ae0 = e0.x*w00.x + e0.y*w00.y + e0.z*w00.z + e0.w*w00.w
                  + e1.x*w01.x + e1.y*w01.y + e1.z*w01.z + e1.w*w01.w;
        float ae1 = e0.x*w10.x + e0.y*w10.y + e0.z*w10.z + e0.w*w10.w
                  + e1.x*w11.x + e1.y*w11.y + e1.z*w11.z + e1.w*w11.w;
        float v0 = a_src[s * 2 + 0] + a_dst[d * 2 + 0] + ae0;
        float v1 = a_src[s * 2 + 1] + a_dst[d * 2 + 1] + ae1;
        v0 = (v0 >= 0.f) ? v0 : NEG_SLOPE * v0;
        v1 = (v1 >= 0.f) ? v1 : NEG_SLOPE * v1;
        int bk = d >> 9;
        int ofs = atomicAdd(&run[bk], 1);
        staging[basearr[bk] + ofs] = make_uint4((uint)s, (uint)d, f2u(v0), f2u(v1));
    }
}

// ---------------------------------------------------------------------------
// Phase 2: fine scatter within bucket (LDS cursors; L2-absorbed writes).
// ---------------------------------------------------------------------------
__global__ __launch_bounds__(256) void fine_scatter_kernel(
    const int* __restrict__ offsets,
    const uint4* __restrict__ staging, uint4* __restrict__ pairs)
{
    __shared__ int cur[512];
    const int tid = threadIdx.x;
    const int nb0 = blockIdx.x * 512;
    const int ncnt = (NN - nb0 < 512) ? (NN - nb0) : 512;
    for (int i = tid; i < ncnt; i += 256) cur[i] = offsets[nb0 + i];
    __syncthreads();
    const int lo = offsets[nb0];
    const int hi = offsets[nb0 + ncnt];
    for (int j = lo + tid; j < hi; j += 256) {
        uint4 it = staging[j];
        int n = (int)it.y - nb0;
        int pos = atomicAdd(&cur[n], 1);
        pairs[pos] = it;
    }
}

// ---------------------------------------------------------------------------
// Fused edge-softmax + aggregation. One wave per dst node.
// Inner gather broadcasts (src,ex0,ex1) via wave-uniform LDS reads (no shfl).
// ---------------------------------------------------------------------------
__global__ __launch_bounds__(256) void aggregate_fused(
    const int* __restrict__ offsets,
    const uint4* __restrict__ pairs,
    const ushort* __restrict__ hsrc,
    ushort* __restrict__ agg)
{
    __shared__ uint4 stash[4][64];
    int wave = threadIdx.x >> 6, lane = threadIdx.x & 63;
    int node = blockIdx.x * 4 + wave;
    if (node >= NN) return;
    int off = offsets[node], end = offsets[node + 1];
    int n = end - off;
    uint* aggw = (uint*)agg;
    if (n <= 0) { aggw[(size_t)node * 64 + lane] = 0; return; }
    const uint* h2 = (const uint*)hsrc;
    int hh = lane >> 5;

    float acc0 = 0.f, acc1 = 0.f, z0 = 0.f, z1 = 0.f;

    if (n <= 64) {
        uint4 pr = (lane < n) ? pairs[off + lane]
                              : make_uint4(0u, 0u, 0xff800000u, 0xff800000u);
        float m0 = u2f(pr.z), m1 = u2f(pr.w);
#pragma unroll
        for (int o = 32; o > 0; o >>= 1) {
            m0 = fmaxf(m0, __shfl_xor(m0, o));
            m1 = fmaxf(m1, __shfl_xor(m1, o));
        }
        float ex0 = (lane < n) ? __expf(u2f(pr.z) - m0) : 0.f;
        float ex1 = (lane < n) ? __expf(u2f(pr.w) - m1) : 0.f;
        z0 = ex0; z1 = ex1;
        stash[wave][lane] = make_uint4(pr.x, f2u(ex0), f2u(ex1), 0u);
        __builtin_amdgcn_wave_barrier();
#pragma unroll 4
        for (int k = 0; k < n; ++k) {
            uint4 st = stash[wave][k];
            uint p = h2[(size_t)st.x * 64 + lane];
            float w = hh ? u2f(st.z) : u2f(st.y);
            acc0 = fmaf(w, lo_bf(p), acc0);
            acc1 = fmaf(w, hi_bf(p), acc1);
        }
    } else {
        float m0 = -INFINITY, m1 = -INFINITY;
        for (int c0 = 0; c0 < n; c0 += 64) {
            if (c0 + lane < n) {
                uint4 pr = pairs[off + c0 + lane];
                m0 = fmaxf(m0, u2f(pr.z));
                m1 = fmaxf(m1, u2f(pr.w));
            }
        }
#pragma unroll
        for (int o = 32; o > 0; o >>= 1) {
            m0 = fmaxf(m0, __shfl_xor(m0, o));
            m1 = fmaxf(m1, __shfl_xor(m1, o));
        }
        for (int c0 = 0; c0 < n; c0 += 64) {
            int cn = n - c0; if (cn > 64) cn = 64;
            uint srcv = 0; float ex0 = 0.f, ex1 = 0.f;
            if (lane < cn) {
                uint4 pr = pairs[off + c0 + lane];
                srcv = pr.x;
                ex0 = __expf(u2f(pr.z) - m0);
                ex1 = __expf(u2f(pr.w) - m1);
                z0 += ex0; z1 += ex1;
            }
            stash[wave][lane] = make_uint4(srcv, f2u(ex0), f2u(ex1), 0u);
            __builtin_amdgcn_wave_barrier();
#pragma unroll 4
            for (int k = 0; k < cn; ++k) {
                uint4 st = stash[wave][k];
                uint p = h2[(size_t)st.x * 64 + lane];
                float w = hh ? u2f(st.z) : u2f(st.y);
                acc0 = fmaf(w, lo_bf(p), acc0);
                acc1 = fmaf(w, hi_bf(p), acc1);
            }
            __builtin_amdgcn_wave_barrier();
        }
    }

#pragma unroll
    for (int o = 32; o > 0; o >>= 1) {
        z0 += __shfl_xor(z0, o);
        z1 += __shfl_xor(z1, o);
    }
    float zi = hh ? ((z1 > 0.f) ? 1.f / z1 : 0.f)
                  : ((z0 > 0.f) ? 1.f / z0 : 0.f);
    float r0 = acc0 * zi;
    float r1 = acc1 * zi;
    aggw[(size_t)node * 64 + lane] = ((uint)f2bf(r1) << 16) | (uint)f2bf(r0);
}

// ---------------------------------------------------------------------------
extern "C" void kernel_launch(void* const* d_in, const int* in_sizes, int n_in,
                              void* d_out, int out_size, void* d_ws, size_t ws_size,
                              hipStream_t stream) {
    (void)in_sizes; (void)n_in; (void)out_size; (void)ws_size;
    const float* feat_src  = (const float*)d_in[0];
    const float* feat_edge = (const float*)d_in[1];
    const int*   edge_src  = (const int*)d_in[2];
    const int*   edge_dst  = (const int*)d_in[3];
    const float* W_src     = (const float*)d_in[4];
    const float* W_dst     = (const float*)d_in[5];
    const float* b_dst     = (const float*)d_in[6];
    const float* W_attn_src  = (const float*)d_in[7];
    const float* W_attn_dst  = (const float*)d_in[8];
    const float* W_attn_edge = (const float*)d_in[9];
    const float* W_ngnn    = (const float*)d_in[10];
    const float* b_ngnn    = (const float*)d_in[11];
    float* out = (float*)d_out;

    char* base = (char*)d_ws;
    size_t off = 0;
    auto take = [&](size_t bytes) -> void* {
        void* p = base + off;
        off = (off + bytes + 511) & ~(size_t)511;
        return p;
    };
    ushort* feat_bf  = (ushort*)take((size_t)NN * DD * 2);    // 51.2 MB
    ushort* h_src_bf = (ushort*)take((size_t)NN * HF * 2);    // 25.6 MB
    uint4*  staging  = (uint4*)take((size_t)EE * 16);         // 25.6 MB
    uint4*  pairs    = (uint4*)take((size_t)EE * 16);         // 25.6 MB
    float*  a_src_b  = (float*)take((size_t)NN * 2 * 4);
    float*  a_dst_b  = (float*)take((size_t)NN * 2 * 4);
    int*    deg      = (int*)take((size_t)NN * 4);
    int*    offsets  = (int*)take((size_t)(NN + 1) * 4);
    int*    bcur     = (int*)take((size_t)NBUCK * 4);
    int*    blockSums= (int*)take(512);
    ushort* Wsrc_bf  = (ushort*)take((size_t)HF * DD * 2);
    ushort* Wdst_bf  = (ushort*)take((size_t)HF * DD * 2);
    ushort* Wngnn_bf = (ushort*)take((size_t)HF * HF * 2);
    ushort* h_dst_bf = (ushort*)staging;   // staging dead after fine_scatter
    ushort* agg_bf   = feat_bf;            // feat_bf dead after dual GEMM

    const int NB_SCAN = (NN + SCAN_ELEMS - 1) / SCAN_ELEMS;   // 98
    const int GB_E  = (EE + 255) / 256;                       // 6250
    const int GB_M  = (NN + 127) / 128;                       // 782
    const int GB_M64= (NN + 63) / 64;                         // 1563
    const int GB_N4 = (NN + 3) / 4;                           // 25000
    const int GB_P1 = (EE + P1_EPB - 1) / P1_EPB;             // 1563
    const int W3_N  = (2 * HF * DD + HF * HF) / 4;            // 20480
    const int GB_W3 = (W3_N + 255) / 256;                     // 80

    // CSR offsets (+ bucket cursor init fused into scan3)
    hipMemsetAsync(deg, 0, (size_t)NN * 4, stream);
    hipLaunchKernelGGL(hist_kernel, dim3(GB_E), dim3(256), 0, stream, edge_dst, deg);
    hipLaunchKernelGGL(scan1_kernel, dim3(NB_SCAN), dim3(256), 0, stream, deg, offsets, blockSums);
    hipLaunchKernelGGL(scan2_kernel, dim3(1), dim3(128), 0, stream, blockSums, NB_SCAN);
    hipLaunchKernelGGL(scan3_kernel, dim3(NB_SCAN), dim3(256), 0, stream, offsets, blockSums, bcur);

    // attn logits + feat->bf16 (fused)
    hipLaunchKernelGGL(attn_logits_kernel, dim3(GB_N4), dim3(256), 0, stream,
                       feat_src, W_attn_src, W_attn_dst, a_src_b, a_dst_b, feat_bf);

    // weight conversions (single launch)
    hipLaunchKernelGGL(f2bf3_kernel, dim3(GB_W3), dim3(256), 0, stream,
                       W_src, W_dst, W_ngnn, Wsrc_bf, Wdst_bf, Wngnn_bf);

    // edge scores + 2-phase counting sort into CSR order
    hipLaunchKernelGGL(bucket_scatter_kernel, dim3(GB_P1), dim3(256), 0, stream,
                       edge_src, edge_dst, feat_edge, a_src_b, a_dst_b, W_attn_edge,
                       bcur, staging);
    hipLaunchKernelGGL(fine_scatter_kernel, dim3(NBUCK), dim3(256), 0, stream,
                       offsets, staging, pairs);

    // dual projection GEMM (feat read once; h_dst lands in staging alias)
    hipLaunchKernelGGL((mfma_gemm_dual<DD>), dim3(GB_M64), dim3(256), 0, stream,
                       Wsrc_bf, Wdst_bf, feat_bf, b_dst, h_src_bf, h_dst_bf);

    // fused softmax + aggregation
    hipLaunchKernelGGL(aggregate_fused, dim3(GB_N4), dim3(256), 0, stream,
                       offsets, pairs, h_src_bf, agg_bf);

    // ngnn + relu + residual -> fp32 out
    hipLaunchKernelGGL((mfma_gemm_ngnn<HF>), dim3(GB_M), dim3(256), 0, stream,
                       Wngnn_bf, agg_bf, b_ngnn, h_dst_bf, out);
}